// Round 6
// baseline (383.912 us; speedup 1.0000x reference)
//
#include <hip/hip_runtime.h>

// VectorQuantizer: z[32,32,64,64] f32 (BCHW), emb[1024,32] f32.
// out = concat( z_q[32,32,64,64] f32 , idx[131072] stored as f32 values ).
//
// R22: ILP + staging-overlap restructure. Evidence (R16/R18/R21): VALU
// busy-time is ~constant 20-25us across variants; duration tracks per-wave
// independent work. The stall is the per-chunk {barrier; stage; barrier}
// with all waves lockstepped. Fix:
//  - 128 q/block, 2 tiles/wave (fastest measured geometry, R16=57us).
//  - double-buffered LDS (2x17KB=34KB, 4 blocks/CU): issue chunk ch+1
//    global loads into REGS at top of chunk ch, compute ch from buf[cur],
//    ds_write regs->buf[cur^1], ONE barrier (T14 async-split). L2 latency
//    hides under the 16-jt compute. ch-loop fully unrolled => static cur.
//  - scan math unchanged (HW-validated R18/R21): f16 single-MFMA
//    (err 9.2e-5 < MARGIN 1e-4), packed-key low-6 mantissa (ch<<4)|jt,
//    med3 second-min, ballot classify, exact fp32 rescore, in-block fixup.
// 2 kernels: prep_e (4 blocks) + filter (1024 blocks).

#define NUM_EMB 1024
#define EMB_DIM 32
#define HW      4096
#define BATCH   32
#define N_TOT   (BATCH * HW)  // 131072
#define NSPLIT  4
#define CODES_PER (NUM_EMB / NSPLIT)
#define MARGIN  1.0e-4f
#define CHUNK   256

// ws layout
#define OFF_BQ    0u
#define OFF_EH    4096u
#define WS_NEED   69632u
#define WS_NEED_R7 (4096u + 4u * 131072u * 8u)

using f16x8 = __attribute__((ext_vector_type(8))) _Float16;
using f32x4 = __attribute__((ext_vector_type(4))) float;

#define REPEAT32(M) \
    M(0)  M(1)  M(2)  M(3)  M(4)  M(5)  M(6)  M(7)  \
    M(8)  M(9)  M(10) M(11) M(12) M(13) M(14) M(15) \
    M(16) M(17) M(18) M(19) M(20) M(21) M(22) M(23) \
    M(24) M(25) M(26) M(27) M(28) M(29) M(30) M(31)

__device__ __forceinline__ float pairwise_sq32(const float* __restrict__ e) {
    float r0 = __fmul_rn(e[0], e[0]), r1 = __fmul_rn(e[1], e[1]);
    float r2 = __fmul_rn(e[2], e[2]), r3 = __fmul_rn(e[3], e[3]);
    float r4 = __fmul_rn(e[4], e[4]), r5 = __fmul_rn(e[5], e[5]);
    float r6 = __fmul_rn(e[6], e[6]), r7 = __fmul_rn(e[7], e[7]);
#pragma unroll
    for (int i = 8; i < 32; i += 8) {
        r0 = __fadd_rn(r0, __fmul_rn(e[i + 0], e[i + 0]));
        r1 = __fadd_rn(r1, __fmul_rn(e[i + 1], e[i + 1]));
        r2 = __fadd_rn(r2, __fmul_rn(e[i + 2], e[i + 2]));
        r3 = __fadd_rn(r3, __fmul_rn(e[i + 3], e[i + 3]));
        r4 = __fadd_rn(r4, __fmul_rn(e[i + 4], e[i + 4]));
        r5 = __fadd_rn(r5, __fmul_rn(e[i + 5], e[i + 5]));
        r6 = __fadd_rn(r6, __fmul_rn(e[i + 6], e[i + 6]));
        r7 = __fadd_rn(r7, __fmul_rn(e[i + 7], e[i + 7]));
    }
    return __fadd_rn(__fadd_rn(__fadd_rn(r0, r1), __fadd_rn(r2, r3)),
                     __fadd_rn(__fadd_rn(r4, r5), __fadd_rn(r6, r7)));
}

__device__ __forceinline__ void store_row16(unsigned short* dst,
                                            const unsigned short* v) {
    unsigned w[16];
#pragma unroll
    for (int i = 0; i < 16; ++i)
        w[i] = (unsigned)v[2 * i] | ((unsigned)v[2 * i + 1] << 16);
    uint4* d4 = (uint4*)dst;
    d4[0] = make_uint4(w[0], w[1], w[2], w[3]);
    d4[1] = make_uint4(w[4], w[5], w[6], w[7]);
    d4[2] = make_uint4(w[8], w[9], w[10], w[11]);
    d4[3] = make_uint4(w[12], w[13], w[14], w[15]);
}

// ---- prep_e: bq exact + (-2e) f16 ----------------------------------------
__global__ __launch_bounds__(256) void vq_prep_e(
        const float* __restrict__ emb, float* __restrict__ bq,
        unsigned short* __restrict__ eh) {
    const int g = blockIdx.x * 256 + threadIdx.x;
    if (g >= NUM_EMB) return;
    const float* e = emb + g * EMB_DIM;
    bq[g] = pairwise_sq32(e);
    unsigned short h[32];
#pragma unroll
    for (int c = 0; c < 32; ++c) {
        _Float16 hv = (_Float16)(-2.0f * e[c]);   // *2 exact, single RNE round
        h[c] = __builtin_bit_cast(unsigned short, hv);
    }
    store_row16(eh + (size_t)g * 32, h);
}

// ---- exact-rescore building blocks (verified numpy-fp32 chain) ------------
#define LOADZ(c) float z##c = zp[(size_t)(c) * HW];
#define Z_SQ_A()                                                              \
    float r0 = __fmul_rn(z0, z0), r1 = __fmul_rn(z1, z1);                     \
    float r2 = __fmul_rn(z2, z2), r3 = __fmul_rn(z3, z3);                     \
    float r4 = __fmul_rn(z4, z4), r5 = __fmul_rn(z5, z5);                     \
    float r6 = __fmul_rn(z6, z6), r7 = __fmul_rn(z7, z7);                     \
    r0 = __fadd_rn(r0, __fmul_rn(z8,  z8));  r0 = __fadd_rn(r0, __fmul_rn(z16, z16)); \
    r0 = __fadd_rn(r0, __fmul_rn(z24, z24));                                  \
    r1 = __fadd_rn(r1, __fmul_rn(z9,  z9));  r1 = __fadd_rn(r1, __fmul_rn(z17, z17)); \
    r1 = __fadd_rn(r1, __fmul_rn(z25, z25));                                  \
    r2 = __fadd_rn(r2, __fmul_rn(z10, z10)); r2 = __fadd_rn(r2, __fmul_rn(z18, z18)); \
    r2 = __fadd_rn(r2, __fmul_rn(z26, z26));                                  \
    r3 = __fadd_rn(r3, __fmul_rn(z11, z11)); r3 = __fadd_rn(r3, __fmul_rn(z19, z19)); \
    r3 = __fadd_rn(r3, __fmul_rn(z27, z27));                                  \
    r4 = __fadd_rn(r4, __fmul_rn(z12, z12)); r4 = __fadd_rn(r4, __fmul_rn(z20, z20)); \
    r4 = __fadd_rn(r4, __fmul_rn(z28, z28));                                  \
    r5 = __fadd_rn(r5, __fmul_rn(z13, z13)); r5 = __fadd_rn(r5, __fmul_rn(z21, z21)); \
    r5 = __fadd_rn(r5, __fmul_rn(z29, z29));                                  \
    r6 = __fadd_rn(r6, __fmul_rn(z14, z14)); r6 = __fadd_rn(r6, __fmul_rn(z22, z22)); \
    r6 = __fadd_rn(r6, __fmul_rn(z30, z30));                                  \
    r7 = __fadd_rn(r7, __fmul_rn(z15, z15)); r7 = __fadd_rn(r7, __fmul_rn(z23, z23)); \
    r7 = __fadd_rn(r7, __fmul_rn(z31, z31));                                  \
    const float a = __fadd_rn(                                                \
        __fadd_rn(__fadd_rn(r0, r1), __fadd_rn(r2, r3)),                      \
        __fadd_rn(__fadd_rn(r4, r5), __fadd_rn(r6, r7)));

#define FMA1(k) m = __fmaf_rn(z##k, e[(k)], m);
#define EXACT_KEY(jv)                                                         \
    {                                                                         \
        const float* e = emb + (size_t)(jv) * EMB_DIM;                        \
        float m = 0.0f;                                                       \
        REPEAT32(FMA1)                                                        \
        float d = __fsub_rn(__fadd_rn(a, bq[(jv)]), __fmul_rn(2.0f, m));      \
        unsigned u = __float_as_uint(d);                                      \
        u = (u & 0x80000000u) ? ~u : (u | 0x80000000u);                       \
        unsigned long long kk =                                               \
            ((unsigned long long)u << 32) | (unsigned)(jv);                   \
        if (kk < bestk) bestk = kk;                                           \
    }

// ---- mega filter: dbuf scan + classify + rescore + writeback + fixup ------
// Block = 256 thr = 4 waves; wave: 2 tiles (32 q); block: 128 queries.
// LDS: eh buf0 [0,16384), eh buf1 [16384,32768), bq buf0 [32768,33792),
// bq buf1 [33792,34816). 34816 B -> 4 blocks/CU.
__global__ __launch_bounds__(256, 4) void vq_filter(
        const float* __restrict__ z, const float* __restrict__ emb,
        const unsigned short* __restrict__ eh,
        const float* __restrict__ bq,
        float* __restrict__ out_zq, float* __restrict__ out_idx) {
    __shared__ __align__(16) char smem[34816];
    __shared__ int swt[2];
    __shared__ int snB;
    // phase-2 aliases (scan complete, barrier-separated):
    int* scand  = (int*)smem;                  // [0, 2048)    128*4 ints
    int* sdest  = (int*)(smem + 2048);         // [2048, 2560) 128 ints
    int* sBlist = (int*)(smem + 2560);         // [2560, 3072) 128 ints
    unsigned long long* bs =
        (unsigned long long*)(smem + 3072);    // [3072, 5120) 256 u64

    const int tid  = threadIdx.x;
    const int lane = tid & 63;
    const int wv   = tid >> 6;                 // 0..3
    const int cloc = lane & 15, quad = lane >> 4;
    const int qbase = blockIdx.x * 128 + wv * 32;

    // stage chunk 0 into regs (issued before z loads; latencies overlap)
    const uint4* esrc = (const uint4*)eh;      // 1024 uint4 per chunk
    uint4 sreg0 = esrc[tid];
    uint4 sreg1 = esrc[256 + tid];
    uint4 sreg2 = esrc[512 + tid];
    uint4 sreg3 = esrc[768 + tid];
    float breg  = bq[tid];

    // A-fragments from z (f16 RNE); raw floats reloaded in phase 2 (L2-hot)
    f16x8 az[2];
#pragma unroll
    for (int t = 0; t < 2; ++t) {
        const int q  = qbase + t * 16 + cloc;
        const int b  = q >> 12;
        const int hw = q & 4095;
        const float* zb = z + ((size_t)b * EMB_DIM + quad * 8) * HW + hw;
#pragma unroll
        for (int k = 0; k < 8; ++k)
            az[t][k] = (_Float16)zb[(size_t)k * HW];   // v_cvt_f16_f32, RNE
    }

    // write buf0, one barrier
    {
        uint4* dst = (uint4*)smem;
        dst[tid]       = sreg0;
        dst[256 + tid] = sreg1;
        dst[512 + tid] = sreg2;
        dst[768 + tid] = sreg3;
        ((float*)(smem + 32768))[tid] = breg;
    }
    __syncthreads();

    float m1[2][4], m2[2][4];
#pragma unroll
    for (int t = 0; t < 2; ++t)
#pragma unroll
        for (int r = 0; r < 4; ++r) { m1[t][r] = 3.4e38f; m2[t][r] = 3.4e38f; }

    const unsigned km = 0xFFFFFFC0u;   // clear low-6 mantissa bits
    const int fbase = cloc * 64 + quad * 16;   // fragment byte offset in buf

#pragma unroll
    for (int ch = 0; ch < 4; ++ch) {
        const int cur = ch & 1;                // compile-time after unroll

        // issue next-chunk global loads early (hide L2 latency under compute)
        if (ch < 3) {
            const int cb = (ch + 1) * 1024;
            sreg0 = esrc[cb + tid];
            sreg1 = esrc[cb + 256 + tid];
            sreg2 = esrc[cb + 512 + tid];
            sreg3 = esrc[cb + 768 + tid];
            breg  = bq[(ch + 1) * 256 + tid];
        }

        // compute on buf[cur]
        const char*  bufe = smem + cur * 16384;
        const float* sb   = (const float*)(smem + 32768 + cur * 1024);
        float c1[2][4], c2[2][4];
#pragma unroll
        for (int t = 0; t < 2; ++t)
#pragma unroll
            for (int r = 0; r < 4; ++r) { c1[t][r] = 3.4e38f; c2[t][r] = 3.4e38f; }

#pragma unroll
        for (int jt = 0; jt < 16; ++jt) {
            f16x8 ef = *(const f16x8*)(bufe + fbase + jt * 1024); // b128
            const float bqv = sb[jt * 16 + cloc];
#pragma unroll
            for (int t = 0; t < 2; ++t) {
                f32x4 acc = {bqv, bqv, bqv, bqv};
                acc = __builtin_amdgcn_mfma_f32_16x16x32_f16(az[t], ef, acc, 0, 0, 0);
#pragma unroll
                for (int r = 0; r < 4; ++r) {
                    const float kv = __uint_as_float(
                        (__float_as_uint(acc[r]) & km) | (unsigned)jt);
                    c2[t][r] = __builtin_amdgcn_fmed3f(kv, c1[t][r], c2[t][r]);
                    c1[t][r] = fminf(c1[t][r], kv);
                }
            }
        }

        // write next chunk into the other buffer (reads of it were drained
        // at the PREVIOUS barrier), then one barrier
        if (ch < 3) {
            uint4* dst = (uint4*)(smem + (cur ^ 1) * 16384);
            dst[tid]       = sreg0;
            dst[256 + tid] = sreg1;
            dst[512 + tid] = sreg2;
            dst[768 + tid] = sreg3;
            ((float*)(smem + 32768 + (cur ^ 1) * 1024))[tid] = breg;
        }
        __syncthreads();

        // merge chunk minima into global (OR ch bits into packed index)
        const unsigned chb = (unsigned)ch << 4;
#pragma unroll
        for (int t = 0; t < 2; ++t)
#pragma unroll
            for (int r = 0; r < 4; ++r) {
                const float a1 = __uint_as_float(__float_as_uint(c1[t][r]) | chb);
                const float a2 = __uint_as_float(__float_as_uint(c2[t][r]) | chb);
                m2[t][r] = fminf(fmaxf(m1[t][r], a1), fminf(m2[t][r], a2));
                m1[t][r] = fminf(m1[t][r], a1);
            }
    }
    // (last barrier of the ch loop separates scan reads from phase-2 aliases)

    // per-query global min across the 16 cloc lanes (packed floats)
    float g[2][4];
#pragma unroll
    for (int t = 0; t < 2; ++t)
#pragma unroll
        for (int r = 0; r < 4; ++r) g[t][r] = m1[t][r];
#pragma unroll
    for (int off = 1; off < 16; off <<= 1)
#pragma unroll
        for (int t = 0; t < 2; ++t)
#pragma unroll
            for (int r = 0; r < 4; ++r)
                g[t][r] = fminf(g[t][r], __shfl_xor(g[t][r], off, 64));

    // classification -> LDS, no atomics (ballot-prefix candidate slots)
#pragma unroll
    for (int t = 0; t < 2; ++t)
#pragma unroll
        for (int r = 0; r < 4; ++r) {
            const float thr = g[t][r] + MARGIN;
            const int   ql  = wv * 32 + t * 16 + quad * 4 + r;
            const bool  f1  = m1[t][r] <= thr;
            const bool  f2  = m2[t][r] <= thr;
            const unsigned long long b1 = __ballot(f1);
            const unsigned long long b2 = __ballot(f2);
            const unsigned mk1 = (unsigned)(b1 >> (quad * 16)) & 0xFFFFu;
            const unsigned mk2 = (unsigned)(b2 >> (quad * 16)) & 0xFFFFu;
            const int pc  = __popc(mk1);
            const int ldr = __ffs(mk1) - 1;   // mk1 != 0 (global-min lane)
            if (mk2 | (unsigned)(pc > 4)) {
                if (cloc == ldr) sdest[ql] = 5;
            } else {
                if (f1)
                    scand[(ql << 2) + __popc(mk1 & ((1u << cloc) - 1u))] =
                        (int)(__float_as_uint(m1[t][r]) & 63u) * 16 + cloc;
                if (cloc == ldr) sdest[ql] = pc;
            }
        }
    __syncthreads();

    // two-wave compaction (R18-validated) + exact rescore for pc 2..4
    int d = 0, pre = 0, myidx = 0;
    if (tid < 128) {
        d = sdest[tid];
        const unsigned long long mB = __ballot(d == 5);
        pre = (int)__popcll(mB & ((1ull << lane) - 1ull));
        if (lane == 0) swt[tid >> 6] = (int)__popcll(mB);
    }
    __syncthreads();
    if (tid == 0) snB = swt[0] + swt[1];
    if (tid < 128) {
        if (d == 5) {
            sBlist[((tid >> 6) ? swt[0] : 0) + pre] = tid;
        } else if (d == 1) {
            myidx = scand[tid << 2];
        } else {
            // exact rescore; z reloaded from global (L2-hot, coalesced)
            const int n  = blockIdx.x * 128 + tid;
            const int bb = n >> 12;
            const int hh = n & 4095;
            const float* zp = z + (size_t)bb * EMB_DIM * HW + hh;
            REPEAT32(LOADZ)
            Z_SQ_A()
            unsigned long long bestk = ~0ull;
            for (int k = 0; k < d; ++k) {
                const int jv = scand[(tid << 2) + k];
                EXACT_KEY(jv)
            }
            myidx = (int)(unsigned)(bestk & 0xffffffffu);
        }
    }
    __syncthreads();   // sBlist/snB visible to all

    // writeback: idx + z_q for all non-B queries (coalesced across tid)
    if (tid < 128 && d != 5) {
        const int n = blockIdx.x * 128 + tid;
        out_idx[n] = (float)myidx;
        const int bb = n >> 12;
        const int hh = n & 4095;
        const float4* er = (const float4*)(emb + (size_t)myidx * EMB_DIM);
        float* op = out_zq + (size_t)bb * EMB_DIM * HW + hh;
#pragma unroll
        for (int c4 = 0; c4 < 8; ++c4) {
            float4 v = er[c4];
            op[(size_t)(c4 * 4 + 0) * HW] = v.x;
            op[(size_t)(c4 * 4 + 1) * HW] = v.y;
            op[(size_t)(c4 * 4 + 2) * HW] = v.z;
            op[(size_t)(c4 * 4 + 3) * HW] = v.w;
        }
    }

    // in-block fixup: exact full 1024-code scan per local-B query
    const int nB = snB;
    for (int ib = 0; ib < nB; ++ib) {
        const int ql = sBlist[ib];
        const int n  = blockIdx.x * 128 + ql;
        const int bb = n >> 12;
        const int hh = n & 4095;
        const float* zp = z + (size_t)bb * EMB_DIM * HW + hh;  // broadcast
        REPEAT32(LOADZ)
        Z_SQ_A()
        unsigned long long bestk = ~0ull;
#pragma unroll
        for (int k = 0; k < 4; ++k) { const int jv = tid * 4 + k; EXACT_KEY(jv) }
        bs[tid] = bestk;
        __syncthreads();
        for (int off = 128; off > 0; off >>= 1) {
            if (tid < off && bs[tid + off] < bs[tid]) bs[tid] = bs[tid + off];
            __syncthreads();
        }
        const int fb = (int)(unsigned)(bs[0] & 0xffffffffu);
        if (tid == 0) out_idx[n] = (float)fb;
        if (tid < EMB_DIM)
            out_zq[(size_t)bb * EMB_DIM * HW + (size_t)tid * HW + hh] =
                emb[(size_t)fb * EMB_DIM + tid];
        __syncthreads();
    }
}

// ================== proven R7/R5 exhaustive fallback =======================
#define SCAN_GROUP4(j)                                                        \
    {                                                                         \
        const float* e = emb + (size_t)(j) * EMB_DIM;                         \
        const float bq0 = bq[(j) + 0], bq1 = bq[(j) + 1];                     \
        const float bq2 = bq[(j) + 2], bq3 = bq[(j) + 3];                     \
        float m0 = 0.0f, m1 = 0.0f, m2 = 0.0f, m3 = 0.0f;                     \
        REPEAT32(FMA_K)                                                       \
        float d0 = __fsub_rn(__fadd_rn(a, bq0), __fmul_rn(2.0f, m0));         \
        float d1 = __fsub_rn(__fadd_rn(a, bq1), __fmul_rn(2.0f, m1));         \
        float d2 = __fsub_rn(__fadd_rn(a, bq2), __fmul_rn(2.0f, m2));         \
        float d3 = __fsub_rn(__fadd_rn(a, bq3), __fmul_rn(2.0f, m3));         \
        if (d0 < best) { best = d0; bidx = (j) + 0; }                         \
        if (d1 < best) { best = d1; bidx = (j) + 1; }                         \
        if (d2 < best) { best = d2; bidx = (j) + 2; }                         \
        if (d3 < best) { best = d3; bidx = (j) + 3; }                         \
    }
#define FMA_K(k) \
        m0 = __fmaf_rn(z##k, e[0 * EMB_DIM + (k)], m0); \
        m1 = __fmaf_rn(z##k, e[1 * EMB_DIM + (k)], m1); \
        m2 = __fmaf_rn(z##k, e[2 * EMB_DIM + (k)], m2); \
        m3 = __fmaf_rn(z##k, e[3 * EMB_DIM + (k)], m3);

__global__ __launch_bounds__(256) void vq_sqnorm_kernel(
        const float* __restrict__ emb, float* __restrict__ bq) {
    int j = blockIdx.x * 256 + threadIdx.x;
    if (j < NUM_EMB) bq[j] = pairwise_sq32(emb + j * EMB_DIM);
}

__global__ __launch_bounds__(128, 4) void vq_partial_kernel(
        const float* __restrict__ z, const float* __restrict__ emb,
        const float* __restrict__ bq, unsigned long long* __restrict__ pk) {
    const int n  = blockIdx.x * 128 + threadIdx.x;
    const int b  = n >> 12;
    const int hw = n & 4095;
    const float* zp = z + (size_t)b * EMB_DIM * HW + hw;
    REPEAT32(LOADZ)
    Z_SQ_A()
    const int j0 = blockIdx.y * CODES_PER;
    float best = 3.4e38f;
    int   bidx = j0;
    for (int j = j0; j < j0 + CODES_PER; j += 4) SCAN_GROUP4(j)
    pk[(size_t)blockIdx.y * N_TOT + n] =
        ((unsigned long long)__float_as_uint(best) << 32) | (unsigned)bidx;
}

__global__ __launch_bounds__(256, 2) void vq_main_kernel(
        const float* __restrict__ z, const float* __restrict__ emb,
        const float* __restrict__ bq, float* __restrict__ out_zq,
        float* __restrict__ out_idx) {
    const int n  = blockIdx.x * 256 + threadIdx.x;
    const int b  = n >> 12;
    const int hw = n & 4095;
    const float* zp = z + (size_t)b * EMB_DIM * HW + hw;
    REPEAT32(LOADZ)
    Z_SQ_A()
    float best = 3.4e38f;
    int   bidx = 0;
    for (int j = 0; j < NUM_EMB; j += 4) SCAN_GROUP4(j)
    out_idx[n] = (float)bidx;
    const float* eb = emb + (size_t)bidx * EMB_DIM;
    float* op = out_zq + (size_t)b * EMB_DIM * HW + hw;
#pragma unroll
    for (int cc = 0; cc < EMB_DIM; ++cc) op[(size_t)cc * HW] = eb[cc];
}

__global__ __launch_bounds__(256) void vq_combine_kernel(
        const float* __restrict__ emb,
        const unsigned long long* __restrict__ pk,
        float* __restrict__ out_zq, float* __restrict__ out_idx) {
    const int n = blockIdx.x * 256 + threadIdx.x;
    unsigned long long m = pk[n];
#pragma unroll
    for (int y = 1; y < NSPLIT; ++y) {
        unsigned long long v = pk[(size_t)y * N_TOT + n];
        if (v < m) m = v;
    }
    const int bidx = (int)(unsigned)(m & 0xffffffffu);
    out_idx[n] = (float)bidx;
    const int b  = n >> 12;
    const int hw = n & 4095;
    const float* eb = emb + (size_t)bidx * EMB_DIM;
    float* op = out_zq + (size_t)b * EMB_DIM * HW + hw;
#pragma unroll
    for (int cc = 0; cc < EMB_DIM; ++cc) op[(size_t)cc * HW] = eb[cc];
}

extern "C" void kernel_launch(void* const* d_in, const int* in_sizes, int n_in,
                              void* d_out, int out_size, void* d_ws,
                              size_t ws_size, hipStream_t stream) {
    const float* z   = (const float*)d_in[0];
    const float* emb = (const float*)d_in[1];
    char* ws = (char*)d_ws;
    float* out0 = (float*)d_out;
    float* out1 = out0 + (size_t)BATCH * EMB_DIM * HW;

    if (ws_size >= WS_NEED) {
        float*          bq = (float*)(ws + OFF_BQ);
        unsigned short* eh = (unsigned short*)(ws + OFF_EH);

        vq_prep_e<<<4, 256, 0, stream>>>(emb, bq, eh);
        vq_filter<<<N_TOT / 128, 256, 0, stream>>>(z, emb, eh, bq,
                                                   out0, out1);
    } else if (ws_size >= WS_NEED_R7) {
        float* bq = (float*)ws;
        unsigned long long* pk = (unsigned long long*)(ws + 4096);
        vq_sqnorm_kernel<<<NUM_EMB / 256, 256, 0, stream>>>(emb, bq);
        vq_partial_kernel<<<dim3(N_TOT / 128, NSPLIT), 128, 0, stream>>>(
            z, emb, bq, pk);
        vq_combine_kernel<<<N_TOT / 256, 256, 0, stream>>>(emb, pk, out0, out1);
    } else {
        float* bq = (float*)ws;
        vq_sqnorm_kernel<<<NUM_EMB / 256, 256, 0, stream>>>(emb, bq);
        vq_main_kernel<<<N_TOT / 256, 256, 0, stream>>>(z, emb, bq, out0, out1);
    }
}

// Round 8
// 138.943 us; speedup vs baseline: 2.7631x; 2.7631x over previous
//
#include <hip/hip_runtime.h>

// VectorQuantizer: z[32,32,64,64] f32 (BCHW), emb[1024,32] f32.
// out = concat( z_q[32,32,64,64] f32 , idx[131072] stored as f32 values ).
//
// R24 = R23 resubmission. Round-7 bench died in infra ("container failed
// twice", no counters, no pytest output). Audit: kernel cannot hang (all
// barriers block-uniform, all loops bounded, no atomics/spins) and cannot
// fault (scan reads <= 65536 within eh region, bq <= 1023, scand < 512,
// phase-2 identical to R21 which passed). Round-3's container death was
// also followed by a WRONG-VALUE failure (not a hang) -> container deaths
// are infra-correlated, not kernel-correlated. Resubmitting unchanged.
//
// Design (R23): staging-free scan. Evidence R16..R22: VALU busy-time
// ~constant 20-25us; duration = exposed latency of the LDS-staging
// schedule; every staging variant (sync barriers R18/R21, async glds R19,
// reg-dbuf R22 -> 901MB spill) was neutral or catastrophic. The codebook
// eh is 64KB = L2-resident (half L1): read B-fragments DIRECTLY from
// global into regs. Per jt each lane loads 16B at eh + jt*1024 + cloc*64
// + quad*16 (64 lanes = contiguous 1KB, coalesced, L2-hot). Deletes all
// scan LDS, all scan barriers, the chunk structure (jt in [0,64) packs
// straight into the low-6 key bits). Waves free-run; unroll-8 keeps 8
// loads in flight (~640cy compute vs ~250cy L2 latency).
//  - scan math otherwise unchanged (HW-validated R18/R21/R22): f16
//    single-MFMA (err 9.2e-5 < MARGIN 1e-4), packed-key low-6 mantissa,
//    med3 second-min, ballot classify, exact fp32 rescore, in-block fixup.
// 2 kernels: prep_e (4 blocks) + filter (1024 blocks, 128 q/block).

#define NUM_EMB 1024
#define EMB_DIM 32
#define HW      4096
#define BATCH   32
#define N_TOT   (BATCH * HW)  // 131072
#define NSPLIT  4
#define CODES_PER (NUM_EMB / NSPLIT)
#define MARGIN  1.0e-4f

// ws layout
#define OFF_BQ    0u
#define OFF_EH    4096u
#define WS_NEED   69632u
#define WS_NEED_R7 (4096u + 4u * 131072u * 8u)

using f16x8 = __attribute__((ext_vector_type(8))) _Float16;
using f32x4 = __attribute__((ext_vector_type(4))) float;

#define REPEAT32(M) \
    M(0)  M(1)  M(2)  M(3)  M(4)  M(5)  M(6)  M(7)  \
    M(8)  M(9)  M(10) M(11) M(12) M(13) M(14) M(15) \
    M(16) M(17) M(18) M(19) M(20) M(21) M(22) M(23) \
    M(24) M(25) M(26) M(27) M(28) M(29) M(30) M(31)

__device__ __forceinline__ float pairwise_sq32(const float* __restrict__ e) {
    float r0 = __fmul_rn(e[0], e[0]), r1 = __fmul_rn(e[1], e[1]);
    float r2 = __fmul_rn(e[2], e[2]), r3 = __fmul_rn(e[3], e[3]);
    float r4 = __fmul_rn(e[4], e[4]), r5 = __fmul_rn(e[5], e[5]);
    float r6 = __fmul_rn(e[6], e[6]), r7 = __fmul_rn(e[7], e[7]);
#pragma unroll
    for (int i = 8; i < 32; i += 8) {
        r0 = __fadd_rn(r0, __fmul_rn(e[i + 0], e[i + 0]));
        r1 = __fadd_rn(r1, __fmul_rn(e[i + 1], e[i + 1]));
        r2 = __fadd_rn(r2, __fmul_rn(e[i + 2], e[i + 2]));
        r3 = __fadd_rn(r3, __fmul_rn(e[i + 3], e[i + 3]));
        r4 = __fadd_rn(r4, __fmul_rn(e[i + 4], e[i + 4]));
        r5 = __fadd_rn(r5, __fmul_rn(e[i + 5], e[i + 5]));
        r6 = __fadd_rn(r6, __fmul_rn(e[i + 6], e[i + 6]));
        r7 = __fadd_rn(r7, __fmul_rn(e[i + 7], e[i + 7]));
    }
    return __fadd_rn(__fadd_rn(__fadd_rn(r0, r1), __fadd_rn(r2, r3)),
                     __fadd_rn(__fadd_rn(r4, r5), __fadd_rn(r6, r7)));
}

__device__ __forceinline__ void store_row16(unsigned short* dst,
                                            const unsigned short* v) {
    unsigned w[16];
#pragma unroll
    for (int i = 0; i < 16; ++i)
        w[i] = (unsigned)v[2 * i] | ((unsigned)v[2 * i + 1] << 16);
    uint4* d4 = (uint4*)dst;
    d4[0] = make_uint4(w[0], w[1], w[2], w[3]);
    d4[1] = make_uint4(w[4], w[5], w[6], w[7]);
    d4[2] = make_uint4(w[8], w[9], w[10], w[11]);
    d4[3] = make_uint4(w[12], w[13], w[14], w[15]);
}

// ---- prep_e: bq exact + (-2e) f16 ----------------------------------------
__global__ __launch_bounds__(256) void vq_prep_e(
        const float* __restrict__ emb, float* __restrict__ bq,
        unsigned short* __restrict__ eh) {
    const int g = blockIdx.x * 256 + threadIdx.x;
    if (g >= NUM_EMB) return;
    const float* e = emb + g * EMB_DIM;
    bq[g] = pairwise_sq32(e);
    unsigned short h[32];
#pragma unroll
    for (int c = 0; c < 32; ++c) {
        _Float16 hv = (_Float16)(-2.0f * e[c]);   // *2 exact, single RNE round
        h[c] = __builtin_bit_cast(unsigned short, hv);
    }
    store_row16(eh + (size_t)g * 32, h);
}

// ---- exact-rescore building blocks (verified numpy-fp32 chain) ------------
#define LOADZ(c) float z##c = zp[(size_t)(c) * HW];
#define Z_SQ_A()                                                              \
    float r0 = __fmul_rn(z0, z0), r1 = __fmul_rn(z1, z1);                     \
    float r2 = __fmul_rn(z2, z2), r3 = __fmul_rn(z3, z3);                     \
    float r4 = __fmul_rn(z4, z4), r5 = __fmul_rn(z5, z5);                     \
    float r6 = __fmul_rn(z6, z6), r7 = __fmul_rn(z7, z7);                     \
    r0 = __fadd_rn(r0, __fmul_rn(z8,  z8));  r0 = __fadd_rn(r0, __fmul_rn(z16, z16)); \
    r0 = __fadd_rn(r0, __fmul_rn(z24, z24));                                  \
    r1 = __fadd_rn(r1, __fmul_rn(z9,  z9));  r1 = __fadd_rn(r1, __fmul_rn(z17, z17)); \
    r1 = __fadd_rn(r1, __fmul_rn(z25, z25));                                  \
    r2 = __fadd_rn(r2, __fmul_rn(z10, z10)); r2 = __fadd_rn(r2, __fmul_rn(z18, z18)); \
    r2 = __fadd_rn(r2, __fmul_rn(z26, z26));                                  \
    r3 = __fadd_rn(r3, __fmul_rn(z11, z11)); r3 = __fadd_rn(r3, __fmul_rn(z19, z19)); \
    r3 = __fadd_rn(r3, __fmul_rn(z27, z27));                                  \
    r4 = __fadd_rn(r4, __fmul_rn(z12, z12)); r4 = __fadd_rn(r4, __fmul_rn(z20, z20)); \
    r4 = __fadd_rn(r4, __fmul_rn(z28, z28));                                  \
    r5 = __fadd_rn(r5, __fmul_rn(z13, z13)); r5 = __fadd_rn(r5, __fmul_rn(z21, z21)); \
    r5 = __fadd_rn(r5, __fmul_rn(z29, z29));                                  \
    r6 = __fadd_rn(r6, __fmul_rn(z14, z14)); r6 = __fadd_rn(r6, __fmul_rn(z22, z22)); \
    r6 = __fadd_rn(r6, __fmul_rn(z30, z30));                                  \
    r7 = __fadd_rn(r7, __fmul_rn(z15, z15)); r7 = __fadd_rn(r7, __fmul_rn(z23, z23)); \
    r7 = __fadd_rn(r7, __fmul_rn(z31, z31));                                  \
    const float a = __fadd_rn(                                                \
        __fadd_rn(__fadd_rn(r0, r1), __fadd_rn(r2, r3)),                      \
        __fadd_rn(__fadd_rn(r4, r5), __fadd_rn(r6, r7)));

#define FMA1(k) m = __fmaf_rn(z##k, e[(k)], m);
#define EXACT_KEY(jv)                                                         \
    {                                                                         \
        const float* e = emb + (size_t)(jv) * EMB_DIM;                        \
        float m = 0.0f;                                                       \
        REPEAT32(FMA1)                                                        \
        float d = __fsub_rn(__fadd_rn(a, bq[(jv)]), __fmul_rn(2.0f, m));      \
        unsigned u = __float_as_uint(d);                                      \
        u = (u & 0x80000000u) ? ~u : (u | 0x80000000u);                       \
        unsigned long long kk =                                               \
            ((unsigned long long)u << 32) | (unsigned)(jv);                   \
        if (kk < bestk) bestk = kk;                                           \
    }

// ---- mega filter: global-direct scan + classify + rescore + fixup ---------
// Block = 256 thr = 4 waves; wave: 2 tiles (32 q); block: 128 queries.
// No scan LDS, no scan barriers. LDS = 5.2KB phase-2 scratch only.
__global__ __launch_bounds__(256, 4) void vq_filter(
        const float* __restrict__ z, const float* __restrict__ emb,
        const unsigned short* __restrict__ eh,
        const float* __restrict__ bq,
        float* __restrict__ out_zq, float* __restrict__ out_idx) {
    __shared__ int scand[512];                 // 128*4 candidate slots
    __shared__ int sdest[128];
    __shared__ int sBlist[128];
    __shared__ unsigned long long bs[256];
    __shared__ int swt[2];
    __shared__ int snB;

    const int tid  = threadIdx.x;
    const int lane = tid & 63;
    const int wv   = tid >> 6;                 // 0..3
    const int cloc = lane & 15, quad = lane >> 4;
    const int qbase = blockIdx.x * 128 + wv * 32;

    // A-fragments from z (f16 RNE); raw floats reloaded in phase 2 (L2-hot)
    f16x8 az[2];
#pragma unroll
    for (int t = 0; t < 2; ++t) {
        const int q  = qbase + t * 16 + cloc;
        const int b  = q >> 12;
        const int hw = q & 4095;
        const float* zb = z + ((size_t)b * EMB_DIM + quad * 8) * HW + hw;
#pragma unroll
        for (int k = 0; k < 8; ++k)
            az[t][k] = (_Float16)zb[(size_t)k * HW];   // v_cvt_f16_f32, RNE
    }

    float m1[2][4], m2[2][4];
#pragma unroll
    for (int t = 0; t < 2; ++t)
#pragma unroll
        for (int r = 0; r < 4; ++r) { m1[t][r] = 3.4e38f; m2[t][r] = 3.4e38f; }

    const unsigned km = 0xFFFFFFC0u;           // clear low-6 mantissa bits
    // lane's fragment pointer: eh + jt*1024 + cloc*64 + quad*16
    const char* efp = (const char*)eh + cloc * 64 + quad * 16;
    const float* bqp = bq + cloc;

    // scan: 64 independent {load -> MFMA -> update} iterations, no barriers.
    // jt packs directly into the low-6 key bits (decode: (key&63)*16+cloc).
#pragma unroll 8
    for (int jt = 0; jt < 64; ++jt) {
        const f16x8 ef  = *(const f16x8*)(efp + jt * 1024);  // L2/L1-hot 16B
        const float bqv = bqp[jt * 16];
#pragma unroll
        for (int t = 0; t < 2; ++t) {
            f32x4 acc = {bqv, bqv, bqv, bqv};
            acc = __builtin_amdgcn_mfma_f32_16x16x32_f16(az[t], ef, acc, 0, 0, 0);
#pragma unroll
            for (int r = 0; r < 4; ++r) {
                const float kv = __uint_as_float(
                    (__float_as_uint(acc[r]) & km) | (unsigned)jt);
                m2[t][r] = __builtin_amdgcn_fmed3f(kv, m1[t][r], m2[t][r]);
                m1[t][r] = fminf(m1[t][r], kv);
            }
        }
    }

    // per-query global min across the 16 cloc lanes (packed floats)
    float g[2][4];
#pragma unroll
    for (int t = 0; t < 2; ++t)
#pragma unroll
        for (int r = 0; r < 4; ++r) g[t][r] = m1[t][r];
#pragma unroll
    for (int off = 1; off < 16; off <<= 1)
#pragma unroll
        for (int t = 0; t < 2; ++t)
#pragma unroll
            for (int r = 0; r < 4; ++r)
                g[t][r] = fminf(g[t][r], __shfl_xor(g[t][r], off, 64));

    // classification -> LDS, no atomics (ballot-prefix candidate slots)
#pragma unroll
    for (int t = 0; t < 2; ++t)
#pragma unroll
        for (int r = 0; r < 4; ++r) {
            const float thr = g[t][r] + MARGIN;
            const int   ql  = wv * 32 + t * 16 + quad * 4 + r;
            const bool  f1  = m1[t][r] <= thr;
            const bool  f2  = m2[t][r] <= thr;
            const unsigned long long b1 = __ballot(f1);
            const unsigned long long b2 = __ballot(f2);
            const unsigned mk1 = (unsigned)(b1 >> (quad * 16)) & 0xFFFFu;
            const unsigned mk2 = (unsigned)(b2 >> (quad * 16)) & 0xFFFFu;
            const int pc  = __popc(mk1);
            const int ldr = __ffs(mk1) - 1;   // mk1 != 0 (global-min lane)
            if (mk2 | (unsigned)(pc > 4)) {
                if (cloc == ldr) sdest[ql] = 5;
            } else {
                if (f1)
                    scand[(ql << 2) + __popc(mk1 & ((1u << cloc) - 1u))] =
                        (int)(__float_as_uint(m1[t][r]) & 63u) * 16 + cloc;
                if (cloc == ldr) sdest[ql] = pc;
            }
        }
    __syncthreads();

    // two-wave compaction (validated R18/R22) + exact rescore for pc 2..4
    int d = 0, pre = 0, myidx = 0;
    if (tid < 128) {
        d = sdest[tid];
        const unsigned long long mB = __ballot(d == 5);
        pre = (int)__popcll(mB & ((1ull << lane) - 1ull));
        if (lane == 0) swt[tid >> 6] = (int)__popcll(mB);
    }
    __syncthreads();
    if (tid == 0) snB = swt[0] + swt[1];
    if (tid < 128) {
        if (d == 5) {
            sBlist[((tid >> 6) ? swt[0] : 0) + pre] = tid;
        } else if (d == 1) {
            myidx = scand[tid << 2];
        } else {
            // exact rescore; z reloaded from global (L2-hot, coalesced)
            const int n  = blockIdx.x * 128 + tid;
            const int bb = n >> 12;
            const int hh = n & 4095;
            const float* zp = z + (size_t)bb * EMB_DIM * HW + hh;
            REPEAT32(LOADZ)
            Z_SQ_A()
            unsigned long long bestk = ~0ull;
            for (int k = 0; k < d; ++k) {
                const int jv = scand[(tid << 2) + k];
                EXACT_KEY(jv)
            }
            myidx = (int)(unsigned)(bestk & 0xffffffffu);
        }
    }
    __syncthreads();   // sBlist/snB visible to all

    // writeback: idx + z_q for all non-B queries (coalesced across tid)
    if (tid < 128 && d != 5) {
        const int n = blockIdx.x * 128 + tid;
        out_idx[n] = (float)myidx;
        const int bb = n >> 12;
        const int hh = n & 4095;
        const float4* er = (const float4*)(emb + (size_t)myidx * EMB_DIM);
        float* op = out_zq + (size_t)bb * EMB_DIM * HW + hh;
#pragma unroll
        for (int c4 = 0; c4 < 8; ++c4) {
            float4 v = er[c4];
            op[(size_t)(c4 * 4 + 0) * HW] = v.x;
            op[(size_t)(c4 * 4 + 1) * HW] = v.y;
            op[(size_t)(c4 * 4 + 2) * HW] = v.z;
            op[(size_t)(c4 * 4 + 3) * HW] = v.w;
        }
    }

    // in-block fixup: exact full 1024-code scan per local-B query
    const int nB = snB;
    for (int ib = 0; ib < nB; ++ib) {
        const int ql = sBlist[ib];
        const int n  = blockIdx.x * 128 + ql;
        const int bb = n >> 12;
        const int hh = n & 4095;
        const float* zp = z + (size_t)bb * EMB_DIM * HW + hh;  // broadcast
        REPEAT32(LOADZ)
        Z_SQ_A()
        unsigned long long bestk = ~0ull;
#pragma unroll
        for (int k = 0; k < 4; ++k) { const int jv = tid * 4 + k; EXACT_KEY(jv) }
        bs[tid] = bestk;
        __syncthreads();
        for (int off = 128; off > 0; off >>= 1) {
            if (tid < off && bs[tid + off] < bs[tid]) bs[tid] = bs[tid + off];
            __syncthreads();
        }
        const int fb = (int)(unsigned)(bs[0] & 0xffffffffu);
        if (tid == 0) out_idx[n] = (float)fb;
        if (tid < EMB_DIM)
            out_zq[(size_t)bb * EMB_DIM * HW + (size_t)tid * HW + hh] =
                emb[(size_t)fb * EMB_DIM + tid];
        __syncthreads();
    }
}

// ================== proven R7/R5 exhaustive fallback =======================
#define SCAN_GROUP4(j)                                                        \
    {                                                                         \
        const float* e = emb + (size_t)(j) * EMB_DIM;                         \
        const float bq0 = bq[(j) + 0], bq1 = bq[(j) + 1];                     \
        const float bq2 = bq[(j) + 2], bq3 = bq[(j) + 3];                     \
        float m0 = 0.0f, m1 = 0.0f, m2 = 0.0f, m3 = 0.0f;                     \
        REPEAT32(FMA_K)                                                       \
        float d0 = __fsub_rn(__fadd_rn(a, bq0), __fmul_rn(2.0f, m0));         \
        float d1 = __fsub_rn(__fadd_rn(a, bq1), __fmul_rn(2.0f, m1));         \
        float d2 = __fsub_rn(__fadd_rn(a, bq2), __fmul_rn(2.0f, m2));         \
        float d3 = __fsub_rn(__fadd_rn(a, bq3), __fmul_rn(2.0f, m3));         \
        if (d0 < best) { best = d0; bidx = (j) + 0; }                         \
        if (d1 < best) { best = d1; bidx = (j) + 1; }                         \
        if (d2 < best) { best = d2; bidx = (j) + 2; }                         \
        if (d3 < best) { best = d3; bidx = (j) + 3; }                         \
    }
#define FMA_K(k) \
        m0 = __fmaf_rn(z##k, e[0 * EMB_DIM + (k)], m0); \
        m1 = __fmaf_rn(z##k, e[1 * EMB_DIM + (k)], m1); \
        m2 = __fmaf_rn(z##k, e[2 * EMB_DIM + (k)], m2); \
        m3 = __fmaf_rn(z##k, e[3 * EMB_DIM + (k)], m3);

__global__ __launch_bounds__(256) void vq_sqnorm_kernel(
        const float* __restrict__ emb, float* __restrict__ bq) {
    int j = blockIdx.x * 256 + threadIdx.x;
    if (j < NUM_EMB) bq[j] = pairwise_sq32(emb + j * EMB_DIM);
}

__global__ __launch_bounds__(128, 4) void vq_partial_kernel(
        const float* __restrict__ z, const float* __restrict__ emb,
        const float* __restrict__ bq, unsigned long long* __restrict__ pk) {
    const int n  = blockIdx.x * 128 + threadIdx.x;
    const int b  = n >> 12;
    const int hw = n & 4095;
    const float* zp = z + (size_t)b * EMB_DIM * HW + hw;
    REPEAT32(LOADZ)
    Z_SQ_A()
    const int j0 = blockIdx.y * CODES_PER;
    float best = 3.4e38f;
    int   bidx = j0;
    for (int j = j0; j < j0 + CODES_PER; j += 4) SCAN_GROUP4(j)
    pk[(size_t)blockIdx.y * N_TOT + n] =
        ((unsigned long long)__float_as_uint(best) << 32) | (unsigned)bidx;
}

__global__ __launch_bounds__(256, 2) void vq_main_kernel(
        const float* __restrict__ z, const float* __restrict__ emb,
        const float* __restrict__ bq, float* __restrict__ out_zq,
        float* __restrict__ out_idx) {
    const int n  = blockIdx.x * 256 + threadIdx.x;
    const int b  = n >> 12;
    const int hw = n & 4095;
    const float* zp = z + (size_t)b * EMB_DIM * HW + hw;
    REPEAT32(LOADZ)
    Z_SQ_A()
    float best = 3.4e38f;
    int   bidx = 0;
    for (int j = 0; j < NUM_EMB; j += 4) SCAN_GROUP4(j)
    out_idx[n] = (float)bidx;
    const float* eb = emb + (size_t)bidx * EMB_DIM;
    float* op = out_zq + (size_t)b * EMB_DIM * HW + hw;
#pragma unroll
    for (int cc = 0; cc < EMB_DIM; ++cc) op[(size_t)cc * HW] = eb[cc];
}

__global__ __launch_bounds__(256) void vq_combine_kernel(
        const float* __restrict__ emb,
        const unsigned long long* __restrict__ pk,
        float* __restrict__ out_zq, float* __restrict__ out_idx) {
    const int n = blockIdx.x * 256 + threadIdx.x;
    unsigned long long m = pk[n];
#pragma unroll
    for (int y = 1; y < NSPLIT; ++y) {
        unsigned long long v = pk[(size_t)y * N_TOT + n];
        if (v < m) m = v;
    }
    const int bidx = (int)(unsigned)(m & 0xffffffffu);
    out_idx[n] = (float)bidx;
    const int b  = n >> 12;
    const int hw = n & 4095;
    const float* eb = emb + (size_t)bidx * EMB_DIM;
    float* op = out_zq + (size_t)b * EMB_DIM * HW + hw;
#pragma unroll
    for (int cc = 0; cc < EMB_DIM; ++cc) op[(size_t)cc * HW] = eb[cc];
}

extern "C" void kernel_launch(void* const* d_in, const int* in_sizes, int n_in,
                              void* d_out, int out_size, void* d_ws,
                              size_t ws_size, hipStream_t stream) {
    const float* z   = (const float*)d_in[0];
    const float* emb = (const float*)d_in[1];
    char* ws = (char*)d_ws;
    float* out0 = (float*)d_out;
    float* out1 = out0 + (size_t)BATCH * EMB_DIM * HW;

    if (ws_size >= WS_NEED) {
        float*          bq = (float*)(ws + OFF_BQ);
        unsigned short* eh = (unsigned short*)(ws + OFF_EH);

        vq_prep_e<<<4, 256, 0, stream>>>(emb, bq, eh);
        vq_filter<<<N_TOT / 128, 256, 0, stream>>>(z, emb, eh, bq,
                                                   out0, out1);
    } else if (ws_size >= WS_NEED_R7) {
        float* bq = (float*)ws;
        unsigned long long* pk = (unsigned long long*)(ws + 4096);
        vq_sqnorm_kernel<<<NUM_EMB / 256, 256, 0, stream>>>(emb, bq);
        vq_partial_kernel<<<dim3(N_TOT / 128, NSPLIT), 128, 0, stream>>>(
            z, emb, bq, pk);
        vq_combine_kernel<<<N_TOT / 256, 256, 0, stream>>>(emb, pk, out0, out1);
    } else {
        float* bq = (float*)ws;
        vq_sqnorm_kernel<<<NUM_EMB / 256, 256, 0, stream>>>(emb, bq);
        vq_main_kernel<<<N_TOT / 256, 256, 0, stream>>>(z, emb, bq, out0, out1);
    }
}

// Round 9
// 132.990 us; speedup vs baseline: 2.8868x; 1.0448x over previous
//
#include <hip/hip_runtime.h>

// VectorQuantizer: z[32,32,64,64] f32 (BCHW), emb[1024,32] f32.
// out = concat( z_q[32,32,64,64] f32 , idx[131072] stored as f32 values ).
//
// R25: explicit depth-4 software-pipelined scan. R24 post-mortem: scan is
// latency-bound at 27% VALUBusy; VGPR_Count=64 proves the compiler
// serialized the "unroll 8" loads (8 in-flight ef need >=80 VGPR; its
// 8-wave occupancy heuristic won, but the grid only supplies 4 waves/SIMD
// -> neither ILP nor TLP). Fix: hand-rolled pipeline with NAMED registers
// ef0..ef3 / bq0..bq3, main loop jt+=4 pinned with unroll 1 (R22 lesson:
// big unrolls let the scheduler hoist loads -> spill). Load-to-use
// distance = 3 bodies (~240cy independent work) covers the ~200cy L2 hit.
// Everything else byte-identical to R24 (passed, absmax 3.81e-06):
//  - global-direct scan (eh 64KB L2-resident), no scan LDS/barriers
//  - f16 single-MFMA (err 9.2e-5 < MARGIN 1e-4), packed-key low-6
//    mantissa jt, med3 second-min, ballot classify, exact fp32 rescore,
//    in-block fixup.
// 2 kernels: prep_e (4 blocks) + filter (1024 blocks, 128 q/block).

#define NUM_EMB 1024
#define EMB_DIM 32
#define HW      4096
#define BATCH   32
#define N_TOT   (BATCH * HW)  // 131072
#define NSPLIT  4
#define CODES_PER (NUM_EMB / NSPLIT)
#define MARGIN  1.0e-4f

// ws layout
#define OFF_BQ    0u
#define OFF_EH    4096u
#define WS_NEED   69632u
#define WS_NEED_R7 (4096u + 4u * 131072u * 8u)

using f16x8 = __attribute__((ext_vector_type(8))) _Float16;
using f32x4 = __attribute__((ext_vector_type(4))) float;

#define REPEAT32(M) \
    M(0)  M(1)  M(2)  M(3)  M(4)  M(5)  M(6)  M(7)  \
    M(8)  M(9)  M(10) M(11) M(12) M(13) M(14) M(15) \
    M(16) M(17) M(18) M(19) M(20) M(21) M(22) M(23) \
    M(24) M(25) M(26) M(27) M(28) M(29) M(30) M(31)

__device__ __forceinline__ float pairwise_sq32(const float* __restrict__ e) {
    float r0 = __fmul_rn(e[0], e[0]), r1 = __fmul_rn(e[1], e[1]);
    float r2 = __fmul_rn(e[2], e[2]), r3 = __fmul_rn(e[3], e[3]);
    float r4 = __fmul_rn(e[4], e[4]), r5 = __fmul_rn(e[5], e[5]);
    float r6 = __fmul_rn(e[6], e[6]), r7 = __fmul_rn(e[7], e[7]);
#pragma unroll
    for (int i = 8; i < 32; i += 8) {
        r0 = __fadd_rn(r0, __fmul_rn(e[i + 0], e[i + 0]));
        r1 = __fadd_rn(r1, __fmul_rn(e[i + 1], e[i + 1]));
        r2 = __fadd_rn(r2, __fmul_rn(e[i + 2], e[i + 2]));
        r3 = __fadd_rn(r3, __fmul_rn(e[i + 3], e[i + 3]));
        r4 = __fadd_rn(r4, __fmul_rn(e[i + 4], e[i + 4]));
        r5 = __fadd_rn(r5, __fmul_rn(e[i + 5], e[i + 5]));
        r6 = __fadd_rn(r6, __fmul_rn(e[i + 6], e[i + 6]));
        r7 = __fadd_rn(r7, __fmul_rn(e[i + 7], e[i + 7]));
    }
    return __fadd_rn(__fadd_rn(__fadd_rn(r0, r1), __fadd_rn(r2, r3)),
                     __fadd_rn(__fadd_rn(r4, r5), __fadd_rn(r6, r7)));
}

__device__ __forceinline__ void store_row16(unsigned short* dst,
                                            const unsigned short* v) {
    unsigned w[16];
#pragma unroll
    for (int i = 0; i < 16; ++i)
        w[i] = (unsigned)v[2 * i] | ((unsigned)v[2 * i + 1] << 16);
    uint4* d4 = (uint4*)dst;
    d4[0] = make_uint4(w[0], w[1], w[2], w[3]);
    d4[1] = make_uint4(w[4], w[5], w[6], w[7]);
    d4[2] = make_uint4(w[8], w[9], w[10], w[11]);
    d4[3] = make_uint4(w[12], w[13], w[14], w[15]);
}

// ---- prep_e: bq exact + (-2e) f16 ----------------------------------------
__global__ __launch_bounds__(256) void vq_prep_e(
        const float* __restrict__ emb, float* __restrict__ bq,
        unsigned short* __restrict__ eh) {
    const int g = blockIdx.x * 256 + threadIdx.x;
    if (g >= NUM_EMB) return;
    const float* e = emb + g * EMB_DIM;
    bq[g] = pairwise_sq32(e);
    unsigned short h[32];
#pragma unroll
    for (int c = 0; c < 32; ++c) {
        _Float16 hv = (_Float16)(-2.0f * e[c]);   // *2 exact, single RNE round
        h[c] = __builtin_bit_cast(unsigned short, hv);
    }
    store_row16(eh + (size_t)g * 32, h);
}

// ---- exact-rescore building blocks (verified numpy-fp32 chain) ------------
#define LOADZ(c) float z##c = zp[(size_t)(c) * HW];
#define Z_SQ_A()                                                              \
    float r0 = __fmul_rn(z0, z0), r1 = __fmul_rn(z1, z1);                     \
    float r2 = __fmul_rn(z2, z2), r3 = __fmul_rn(z3, z3);                     \
    float r4 = __fmul_rn(z4, z4), r5 = __fmul_rn(z5, z5);                     \
    float r6 = __fmul_rn(z6, z6), r7 = __fmul_rn(z7, z7);                     \
    r0 = __fadd_rn(r0, __fmul_rn(z8,  z8));  r0 = __fadd_rn(r0, __fmul_rn(z16, z16)); \
    r0 = __fadd_rn(r0, __fmul_rn(z24, z24));                                  \
    r1 = __fadd_rn(r1, __fmul_rn(z9,  z9));  r1 = __fadd_rn(r1, __fmul_rn(z17, z17)); \
    r1 = __fadd_rn(r1, __fmul_rn(z25, z25));                                  \
    r2 = __fadd_rn(r2, __fmul_rn(z10, z10)); r2 = __fadd_rn(r2, __fmul_rn(z18, z18)); \
    r2 = __fadd_rn(r2, __fmul_rn(z26, z26));                                  \
    r3 = __fadd_rn(r3, __fmul_rn(z11, z11)); r3 = __fadd_rn(r3, __fmul_rn(z19, z19)); \
    r3 = __fadd_rn(r3, __fmul_rn(z27, z27));                                  \
    r4 = __fadd_rn(r4, __fmul_rn(z12, z12)); r4 = __fadd_rn(r4, __fmul_rn(z20, z20)); \
    r4 = __fadd_rn(r4, __fmul_rn(z28, z28));                                  \
    r5 = __fadd_rn(r5, __fmul_rn(z13, z13)); r5 = __fadd_rn(r5, __fmul_rn(z21, z21)); \
    r5 = __fadd_rn(r5, __fmul_rn(z29, z29));                                  \
    r6 = __fadd_rn(r6, __fmul_rn(z14, z14)); r6 = __fadd_rn(r6, __fmul_rn(z22, z22)); \
    r6 = __fadd_rn(r6, __fmul_rn(z30, z30));                                  \
    r7 = __fadd_rn(r7, __fmul_rn(z15, z15)); r7 = __fadd_rn(r7, __fmul_rn(z23, z23)); \
    r7 = __fadd_rn(r7, __fmul_rn(z31, z31));                                  \
    const float a = __fadd_rn(                                                \
        __fadd_rn(__fadd_rn(r0, r1), __fadd_rn(r2, r3)),                      \
        __fadd_rn(__fadd_rn(r4, r5), __fadd_rn(r6, r7)));

#define FMA1(k) m = __fmaf_rn(z##k, e[(k)], m);
#define EXACT_KEY(jv)                                                         \
    {                                                                         \
        const float* e = emb + (size_t)(jv) * EMB_DIM;                        \
        float m = 0.0f;                                                       \
        REPEAT32(FMA1)                                                        \
        float d = __fsub_rn(__fadd_rn(a, bq[(jv)]), __fmul_rn(2.0f, m));      \
        unsigned u = __float_as_uint(d);                                      \
        u = (u & 0x80000000u) ? ~u : (u | 0x80000000u);                       \
        unsigned long long kk =                                               \
            ((unsigned long long)u << 32) | (unsigned)(jv);                   \
        if (kk < bestk) bestk = kk;                                           \
    }

// scan body: one code tile (16 codes) against both query tiles
#define SBODY(EF, BQV, JTV)                                                   \
    {                                                                         \
        _Pragma("unroll")                                                     \
        for (int t = 0; t < 2; ++t) {                                         \
            f32x4 acc = {(BQV), (BQV), (BQV), (BQV)};                         \
            acc = __builtin_amdgcn_mfma_f32_16x16x32_f16(az[t], (EF), acc,    \
                                                         0, 0, 0);            \
            _Pragma("unroll")                                                 \
            for (int r = 0; r < 4; ++r) {                                     \
                const float kv = __uint_as_float(                             \
                    (__float_as_uint(acc[r]) & km) | (unsigned)(JTV));        \
                m2[t][r] = __builtin_amdgcn_fmed3f(kv, m1[t][r], m2[t][r]);   \
                m1[t][r] = fminf(m1[t][r], kv);                               \
            }                                                                 \
        }                                                                     \
    }

// ---- mega filter: pipelined global-direct scan + classify + fixup ---------
// Block = 256 thr = 4 waves; wave: 2 tiles (32 q); block: 128 queries.
// No scan LDS, no scan barriers. LDS = 5.2KB phase-2 scratch only.
__global__ __launch_bounds__(256, 4) void vq_filter(
        const float* __restrict__ z, const float* __restrict__ emb,
        const unsigned short* __restrict__ eh,
        const float* __restrict__ bq,
        float* __restrict__ out_zq, float* __restrict__ out_idx) {
    __shared__ int scand[512];                 // 128*4 candidate slots
    __shared__ int sdest[128];
    __shared__ int sBlist[128];
    __shared__ unsigned long long bs[256];
    __shared__ int swt[2];
    __shared__ int snB;

    const int tid  = threadIdx.x;
    const int lane = tid & 63;
    const int wv   = tid >> 6;                 // 0..3
    const int cloc = lane & 15, quad = lane >> 4;
    const int qbase = blockIdx.x * 128 + wv * 32;

    // A-fragments from z (f16 RNE); raw floats reloaded in phase 2 (L2-hot)
    f16x8 az[2];
#pragma unroll
    for (int t = 0; t < 2; ++t) {
        const int q  = qbase + t * 16 + cloc;
        const int b  = q >> 12;
        const int hw = q & 4095;
        const float* zb = z + ((size_t)b * EMB_DIM + quad * 8) * HW + hw;
#pragma unroll
        for (int k = 0; k < 8; ++k)
            az[t][k] = (_Float16)zb[(size_t)k * HW];   // v_cvt_f16_f32, RNE
    }

    float m1[2][4], m2[2][4];
#pragma unroll
    for (int t = 0; t < 2; ++t)
#pragma unroll
        for (int r = 0; r < 4; ++r) { m1[t][r] = 3.4e38f; m2[t][r] = 3.4e38f; }

    const unsigned km = 0xFFFFFFC0u;           // clear low-6 mantissa bits
    // lane's fragment pointer: eh + jt*1024 + cloc*64 + quad*16
    const char* efp = (const char*)eh + cloc * 64 + quad * 16;
    const float* bqp = bq + cloc;

    // depth-4 software pipeline, named registers (forces 4 loads in flight;
    // the compiler's 64-VGPR heuristic serialized the R24 "unroll 8" form).
    f16x8 ef0 = *(const f16x8*)(efp + 0 * 1024);
    f16x8 ef1 = *(const f16x8*)(efp + 1 * 1024);
    f16x8 ef2 = *(const f16x8*)(efp + 2 * 1024);
    f16x8 ef3 = *(const f16x8*)(efp + 3 * 1024);
    float bq0 = bqp[0 * 16], bq1 = bqp[1 * 16];
    float bq2 = bqp[2 * 16], bq3 = bqp[3 * 16];

#pragma unroll 1
    for (int jt = 0; jt < 60; jt += 4) {
        SBODY(ef0, bq0, jt + 0)
        ef0 = *(const f16x8*)(efp + (jt + 4) * 1024); bq0 = bqp[(jt + 4) * 16];
        SBODY(ef1, bq1, jt + 1)
        ef1 = *(const f16x8*)(efp + (jt + 5) * 1024); bq1 = bqp[(jt + 5) * 16];
        SBODY(ef2, bq2, jt + 2)
        ef2 = *(const f16x8*)(efp + (jt + 6) * 1024); bq2 = bqp[(jt + 6) * 16];
        SBODY(ef3, bq3, jt + 3)
        ef3 = *(const f16x8*)(efp + (jt + 7) * 1024); bq3 = bqp[(jt + 7) * 16];
    }
    SBODY(ef0, bq0, 60)
    SBODY(ef1, bq1, 61)
    SBODY(ef2, bq2, 62)
    SBODY(ef3, bq3, 63)

    // per-query global min across the 16 cloc lanes (packed floats)
    float g[2][4];
#pragma unroll
    for (int t = 0; t < 2; ++t)
#pragma unroll
        for (int r = 0; r < 4; ++r) g[t][r] = m1[t][r];
#pragma unroll
    for (int off = 1; off < 16; off <<= 1)
#pragma unroll
        for (int t = 0; t < 2; ++t)
#pragma unroll
            for (int r = 0; r < 4; ++r)
                g[t][r] = fminf(g[t][r], __shfl_xor(g[t][r], off, 64));

    // classification -> LDS, no atomics (ballot-prefix candidate slots)
#pragma unroll
    for (int t = 0; t < 2; ++t)
#pragma unroll
        for (int r = 0; r < 4; ++r) {
            const float thr = g[t][r] + MARGIN;
            const int   ql  = wv * 32 + t * 16 + quad * 4 + r;
            const bool  f1  = m1[t][r] <= thr;
            const bool  f2  = m2[t][r] <= thr;
            const unsigned long long b1 = __ballot(f1);
            const unsigned long long b2 = __ballot(f2);
            const unsigned mk1 = (unsigned)(b1 >> (quad * 16)) & 0xFFFFu;
            const unsigned mk2 = (unsigned)(b2 >> (quad * 16)) & 0xFFFFu;
            const int pc  = __popc(mk1);
            const int ldr = __ffs(mk1) - 1;   // mk1 != 0 (global-min lane)
            if (mk2 | (unsigned)(pc > 4)) {
                if (cloc == ldr) sdest[ql] = 5;
            } else {
                if (f1)
                    scand[(ql << 2) + __popc(mk1 & ((1u << cloc) - 1u))] =
                        (int)(__float_as_uint(m1[t][r]) & 63u) * 16 + cloc;
                if (cloc == ldr) sdest[ql] = pc;
            }
        }
    __syncthreads();

    // two-wave compaction (validated R18/R24) + exact rescore for pc 2..4
    int d = 0, pre = 0, myidx = 0;
    if (tid < 128) {
        d = sdest[tid];
        const unsigned long long mB = __ballot(d == 5);
        pre = (int)__popcll(mB & ((1ull << lane) - 1ull));
        if (lane == 0) swt[tid >> 6] = (int)__popcll(mB);
    }
    __syncthreads();
    if (tid == 0) snB = swt[0] + swt[1];
    if (tid < 128) {
        if (d == 5) {
            sBlist[((tid >> 6) ? swt[0] : 0) + pre] = tid;
        } else if (d == 1) {
            myidx = scand[tid << 2];
        } else {
            // exact rescore; z reloaded from global (L2-hot, coalesced)
            const int n  = blockIdx.x * 128 + tid;
            const int bb = n >> 12;
            const int hh = n & 4095;
            const float* zp = z + (size_t)bb * EMB_DIM * HW + hh;
            REPEAT32(LOADZ)
            Z_SQ_A()
            unsigned long long bestk = ~0ull;
            for (int k = 0; k < d; ++k) {
                const int jv = scand[(tid << 2) + k];
                EXACT_KEY(jv)
            }
            myidx = (int)(unsigned)(bestk & 0xffffffffu);
        }
    }
    __syncthreads();   // sBlist/snB visible to all

    // writeback: idx + z_q for all non-B queries (coalesced across tid)
    if (tid < 128 && d != 5) {
        const int n = blockIdx.x * 128 + tid;
        out_idx[n] = (float)myidx;
        const int bb = n >> 12;
        const int hh = n & 4095;
        const float4* er = (const float4*)(emb + (size_t)myidx * EMB_DIM);
        float* op = out_zq + (size_t)bb * EMB_DIM * HW + hh;
#pragma unroll
        for (int c4 = 0; c4 < 8; ++c4) {
            float4 v = er[c4];
            op[(size_t)(c4 * 4 + 0) * HW] = v.x;
            op[(size_t)(c4 * 4 + 1) * HW] = v.y;
            op[(size_t)(c4 * 4 + 2) * HW] = v.z;
            op[(size_t)(c4 * 4 + 3) * HW] = v.w;
        }
    }

    // in-block fixup: exact full 1024-code scan per local-B query
    const int nB = snB;
    for (int ib = 0; ib < nB; ++ib) {
        const int ql = sBlist[ib];
        const int n  = blockIdx.x * 128 + ql;
        const int bb = n >> 12;
        const int hh = n & 4095;
        const float* zp = z + (size_t)bb * EMB_DIM * HW + hh;  // broadcast
        REPEAT32(LOADZ)
        Z_SQ_A()
        unsigned long long bestk = ~0ull;
#pragma unroll
        for (int k = 0; k < 4; ++k) { const int jv = tid * 4 + k; EXACT_KEY(jv) }
        bs[tid] = bestk;
        __syncthreads();
        for (int off = 128; off > 0; off >>= 1) {
            if (tid < off && bs[tid + off] < bs[tid]) bs[tid] = bs[tid + off];
            __syncthreads();
        }
        const int fb = (int)(unsigned)(bs[0] & 0xffffffffu);
        if (tid == 0) out_idx[n] = (float)fb;
        if (tid < EMB_DIM)
            out_zq[(size_t)bb * EMB_DIM * HW + (size_t)tid * HW + hh] =
                emb[(size_t)fb * EMB_DIM + tid];
        __syncthreads();
    }
}

// ================== proven R7/R5 exhaustive fallback =======================
#define SCAN_GROUP4(j)                                                        \
    {                                                                         \
        const float* e = emb + (size_t)(j) * EMB_DIM;                         \
        const float bq0 = bq[(j) + 0], bq1 = bq[(j) + 1];                     \
        const float bq2 = bq[(j) + 2], bq3 = bq[(j) + 3];                     \
        float m0 = 0.0f, m1 = 0.0f, m2 = 0.0f, m3 = 0.0f;                     \
        REPEAT32(FMA_K)                                                       \
        float d0 = __fsub_rn(__fadd_rn(a, bq0), __fmul_rn(2.0f, m0));         \
        float d1 = __fsub_rn(__fadd_rn(a, bq1), __fmul_rn(2.0f, m1));         \
        float d2 = __fsub_rn(__fadd_rn(a, bq2), __fmul_rn(2.0f, m2));         \
        float d3 = __fsub_rn(__fadd_rn(a, bq3), __fmul_rn(2.0f, m3));         \
        if (d0 < best) { best = d0; bidx = (j) + 0; }                         \
        if (d1 < best) { best = d1; bidx = (j) + 1; }                         \
        if (d2 < best) { best = d2; bidx = (j) + 2; }                         \
        if (d3 < best) { best = d3; bidx = (j) + 3; }                         \
    }
#define FMA_K(k) \
        m0 = __fmaf_rn(z##k, e[0 * EMB_DIM + (k)], m0); \
        m1 = __fmaf_rn(z##k, e[1 * EMB_DIM + (k)], m1); \
        m2 = __fmaf_rn(z##k, e[2 * EMB_DIM + (k)], m2); \
        m3 = __fmaf_rn(z##k, e[3 * EMB_DIM + (k)], m3);

__global__ __launch_bounds__(256) void vq_sqnorm_kernel(
        const float* __restrict__ emb, float* __restrict__ bq) {
    int j = blockIdx.x * 256 + threadIdx.x;
    if (j < NUM_EMB) bq[j] = pairwise_sq32(emb + j * EMB_DIM);
}

__global__ __launch_bounds__(128, 4) void vq_partial_kernel(
        const float* __restrict__ z, const float* __restrict__ emb,
        const float* __restrict__ bq, unsigned long long* __restrict__ pk) {
    const int n  = blockIdx.x * 128 + threadIdx.x;
    const int b  = n >> 12;
    const int hw = n & 4095;
    const float* zp = z + (size_t)b * EMB_DIM * HW + hw;
    REPEAT32(LOADZ)
    Z_SQ_A()
    const int j0 = blockIdx.y * CODES_PER;
    float best = 3.4e38f;
    int   bidx = j0;
    for (int j = j0; j < j0 + CODES_PER; j += 4) SCAN_GROUP4(j)
    pk[(size_t)blockIdx.y * N_TOT + n] =
        ((unsigned long long)__float_as_uint(best) << 32) | (unsigned)bidx;
}

__global__ __launch_bounds__(256, 2) void vq_main_kernel(
        const float* __restrict__ z, const float* __restrict__ emb,
        const float* __restrict__ bq, float* __restrict__ out_zq,
        float* __restrict__ out_idx) {
    const int n  = blockIdx.x * 256 + threadIdx.x;
    const int b  = n >> 12;
    const int hw = n & 4095;
    const float* zp = z + (size_t)b * EMB_DIM * HW + hw;
    REPEAT32(LOADZ)
    Z_SQ_A()
    float best = 3.4e38f;
    int   bidx = 0;
    for (int j = 0; j < NUM_EMB; j += 4) SCAN_GROUP4(j)
    out_idx[n] = (float)bidx;
    const float* eb = emb + (size_t)bidx * EMB_DIM;
    float* op = out_zq + (size_t)b * EMB_DIM * HW + hw;
#pragma unroll
    for (int cc = 0; cc < EMB_DIM; ++cc) op[(size_t)cc * HW] = eb[cc];
}

__global__ __launch_bounds__(256) void vq_combine_kernel(
        const float* __restrict__ emb,
        const unsigned long long* __restrict__ pk,
        float* __restrict__ out_zq, float* __restrict__ out_idx) {
    const int n = blockIdx.x * 256 + threadIdx.x;
    unsigned long long m = pk[n];
#pragma unroll
    for (int y = 1; y < NSPLIT; ++y) {
        unsigned long long v = pk[(size_t)y * N_TOT + n];
        if (v < m) m = v;
    }
    const int bidx = (int)(unsigned)(m & 0xffffffffu);
    out_idx[n] = (float)bidx;
    const int b  = n >> 12;
    const int hw = n & 4095;
    const float* eb = emb + (size_t)bidx * EMB_DIM;
    float* op = out_zq + (size_t)b * EMB_DIM * HW + hw;
#pragma unroll
    for (int cc = 0; cc < EMB_DIM; ++cc) op[(size_t)cc * HW] = eb[cc];
}

extern "C" void kernel_launch(void* const* d_in, const int* in_sizes, int n_in,
                              void* d_out, int out_size, void* d_ws,
                              size_t ws_size, hipStream_t stream) {
    const float* z   = (const float*)d_in[0];
    const float* emb = (const float*)d_in[1];
    char* ws = (char*)d_ws;
    float* out0 = (float*)d_out;
    float* out1 = out0 + (size_t)BATCH * EMB_DIM * HW;

    if (ws_size >= WS_NEED) {
        float*          bq = (float*)(ws + OFF_BQ);
        unsigned short* eh = (unsigned short*)(ws + OFF_EH);

        vq_prep_e<<<4, 256, 0, stream>>>(emb, bq, eh);
        vq_filter<<<N_TOT / 128, 256, 0, stream>>>(z, emb, eh, bq,
                                                   out0, out1);
    } else if (ws_size >= WS_NEED_R7) {
        float* bq = (float*)ws;
        unsigned long long* pk = (unsigned long long*)(ws + 4096);
        vq_sqnorm_kernel<<<NUM_EMB / 256, 256, 0, stream>>>(emb, bq);
        vq_partial_kernel<<<dim3(N_TOT / 128, NSPLIT), 128, 0, stream>>>(
            z, emb, bq, pk);
        vq_combine_kernel<<<N_TOT / 256, 256, 0, stream>>>(emb, pk, out0, out1);
    } else {
        float* bq = (float*)ws;
        vq_sqnorm_kernel<<<NUM_EMB / 256, 256, 0, stream>>>(emb, bq);
        vq_main_kernel<<<N_TOT / 256, 256, 0, stream>>>(z, emb, bq, out0, out1);
    }
}